// Round 4
// baseline (100.790 us; speedup 1.0000x reference)
//
#include <hip/hip_runtime.h>
#include <math.h>

#define N_NODES 10000
#define DEG1 33          // DEG + self-loop
#define D_EMB 128
#define F_IN 128
#define BATCH 2

typedef short s8v  __attribute__((ext_vector_type(8)));
typedef float f4v  __attribute__((ext_vector_type(4)));

// fp32 -> bf16 round-to-nearest-even (no NaN special-case; inputs are normal)
static __device__ __forceinline__ unsigned short f2bf(float f) {
    unsigned int x = __float_as_uint(f);
    unsigned int r = (x + 0x7fffu + ((x >> 16) & 1u)) >> 16;
    return (unsigned short)r;
}
static __device__ __forceinline__ float bf_lo(unsigned int u) { return __uint_as_float(u << 16); }
static __device__ __forceinline__ float bf_hi(unsigned int u) { return __uint_as_float(u & 0xffff0000u); }

// ---------------------------------------------------------------------------
// Kernel 0 (prep): pack W (128x128 fp32) into bf16 B-fragments for
// mfma_f32_16x16x32_bf16:  B[k = s*32 + (l>>4)*8 + j][n = c*16 + (l&15)]
// layout wtf[((c*4+s)*64 + l)*8 + j]  (16B/lane -> coalesced dwordx4 loads).
// ---------------------------------------------------------------------------
__global__ __launch_bounds__(256) void gat_prep_kernel(
    const float* __restrict__ W, unsigned short* __restrict__ wtf)
{
    const int c = blockIdx.x;
    const int t = threadIdx.x;
    __shared__ float xs[128 * 16];   // W[:, c*16 .. c*16+16)
    #pragma unroll
    for (int r = 0; r < 8; ++r) {
        const int k = r * 16 + (t >> 4);
        const int n = t & 15;
        xs[k * 16 + n] = W[k * 128 + c * 16 + n];
    }
    __syncthreads();
    const int s = t >> 6;    // k-step 0..3
    const int l = t & 63;    // lane
    s8v frag;
    #pragma unroll
    for (int j = 0; j < 8; ++j) {
        const int k = s * 32 + (l >> 4) * 8 + j;
        frag[j] = (short)f2bf(xs[k * 16 + (l & 15)]);
    }
    *(s8v*)&wtf[(((size_t)c * 4 + s) * 64 + l) * 8] = frag;
}

// ---------------------------------------------------------------------------
// Kernel 1: h = X @ W via bf16 MFMA. Wave = 16 rows x 64 cols (col-half):
// 2500 waves (2x R3) for latency hiding; wave pairs in a block share X rows
// (L1 reuse). Partial s/d dots combined via 512B LDS + one barrier.
// h stored bf16, batch-interleaved: hb[(n*2+b)*128 + col].
// ---------------------------------------------------------------------------
__global__ __launch_bounds__(256) void gat_h_kernel(
    const float* __restrict__ X, const unsigned short* __restrict__ wtf,
    const float* __restrict__ Wattn,
    unsigned short* __restrict__ hb, float* __restrict__ s_arr, float* __restrict__ d_arr)
{
    __shared__ float lds_sd[2][2][2][16];   // [rowgroup][colhalf][s|d][row]
    const int wave = threadIdx.x >> 6;
    const int lane = threadIdx.x & 63;
    const int quad = lane >> 4;
    const int mrow = lane & 15;
    const int rg   = wave >> 1;              // row-group within block (0,1)
    const int half = wave & 1;               // col half (0,1)
    const int row0 = (blockIdx.x * 2 + rg) * 16;

    f4v acc[4];
    #pragma unroll
    for (int cc = 0; cc < 4; ++cc) acc[cc] = (f4v){0.f, 0.f, 0.f, 0.f};

    const float* xrow = X + (size_t)(row0 + mrow) * F_IN;
    #pragma unroll
    for (int s = 0; s < 4; ++s) {
        const int k0 = s * 32 + quad * 8;
        const float4 xa = *(const float4*)&xrow[k0];
        const float4 xbv = *(const float4*)&xrow[k0 + 4];
        s8v a;
        a[0] = (short)f2bf(xa.x);  a[1] = (short)f2bf(xa.y);
        a[2] = (short)f2bf(xa.z);  a[3] = (short)f2bf(xa.w);
        a[4] = (short)f2bf(xbv.x); a[5] = (short)f2bf(xbv.y);
        a[6] = (short)f2bf(xbv.z); a[7] = (short)f2bf(xbv.w);
        #pragma unroll
        for (int cc = 0; cc < 4; ++cc) {
            const int c = half * 4 + cc;
            const s8v b = *(const s8v*)&wtf[(((size_t)c * 4 + s) * 64 + lane) * 8];
            acc[cc] = __builtin_amdgcn_mfma_f32_16x16x32_bf16(a, b, acc[cc], 0, 0, 0);
        }
    }

    // ---- store h (bf16, interleaved (n, b)); rows never straddle the batch ----
    const int b = (row0 >= N_NODES) ? 1 : 0;
    #pragma unroll
    for (int r = 0; r < 4; ++r) {
        const int R = row0 + quad * 4 + r;
        const int n = R - b * N_NODES;
        unsigned short* dst = &hb[((size_t)n * 2 + b) * D_EMB + half * 64 + mrow];
        #pragma unroll
        for (int cc = 0; cc < 4; ++cc)
            dst[cc * 16] = f2bf(acc[cc][r]);
    }

    // ---- partial s/d dots over this wave's 64 cols ----
    float as[4], ad[4];
    #pragma unroll
    for (int cc = 0; cc < 4; ++cc) {
        as[cc] = Wattn[(half * 4 + cc) * 16 + mrow];
        ad[cc] = Wattn[D_EMB + (half * 4 + cc) * 16 + mrow];
    }
    #pragma unroll
    for (int r = 0; r < 4; ++r) {
        float sv = 0.f, dv = 0.f;
        #pragma unroll
        for (int cc = 0; cc < 4; ++cc) {
            sv = fmaf(acc[cc][r], as[cc], sv);
            dv = fmaf(acc[cc][r], ad[cc], dv);
        }
        #pragma unroll
        for (int off = 1; off < 16; off <<= 1) {
            sv += __shfl_xor(sv, off, 16);
            dv += __shfl_xor(dv, off, 16);
        }
        if (mrow == 0) {
            lds_sd[rg][half][0][quad * 4 + r] = sv;
            lds_sd[rg][half][1][quad * 4 + r] = dv;
        }
    }
    __syncthreads();
    const int t = threadIdx.x;
    if (t < 64) {
        const int rg2 = t >> 5, r = (t >> 1) & 15, which = t & 1;
        const float val = lds_sd[rg2][0][which][r] + lds_sd[rg2][1][which][r];
        const int row = (blockIdx.x * 2 + rg2) * 16 + r;
        if (which == 0) s_arr[row] = val; else d_arr[row] = val;
    }
}

// ---------------------------------------------------------------------------
// Kernel 2: edge phase. ONE WAVE PER NODE, zero barriers, no LDS.
// Lanes 0..32 compute both batches' scores; denom = butterfly over batch-0
// scores (inv_denom factors out of both batches). Broadcasts via __shfl with
// compile-time lane (v_readlane -> SGPR). Gather: uint2 (8B/lane) covers both
// batches' interleaved bf16 rows (512B) in one instruction per edge.
// Wave handles 4 consecutive nodes; 625 blocks x 4 waves.
// ---------------------------------------------------------------------------
__global__ __launch_bounds__(256) void gat_agg_kernel(
    const uint2* __restrict__ h2, const float* __restrict__ s_arr,
    const float* __restrict__ d_arr, const int* __restrict__ edges,
    float* __restrict__ out)
{
    const int wid  = blockIdx.x * 4 + (threadIdx.x >> 6);   // 0..2499
    const int lane = threadIdx.x & 63;

    for (int it = 0; it < 4; ++it) {
        const int i = wid * 4 + it;   // node

        int dstv = 0; float sc0 = 0.f, sc1 = 0.f;
        if (lane < DEG1) {
            dstv = edges[((size_t)i * DEG1 + lane) * 2 + 1];
            float x0 = s_arr[i] + d_arr[dstv];
            float x1 = s_arr[N_NODES + i] + d_arr[N_NODES + dstv];
            x0 = (x0 >= 0.f) ? x0 : 0.2f * x0;
            x1 = (x1 >= 0.f) ? x1 : 0.2f * x1;
            x0 = fminf(fmaxf(x0, -2.f), 2.f);
            x1 = fminf(fmaxf(x1, -2.f), 2.f);
            sc0 = __expf(x0);
            sc1 = __expf(x1);
        }
        float dsum = sc0;
        #pragma unroll
        for (int off = 1; off < 64; off <<= 1) dsum += __shfl_xor(dsum, off, 64);
        const float inv = 1.f / dsum;

        const float4 zero = make_float4(0.f, 0.f, 0.f, 0.f);
        float4 acc = zero;
        #pragma unroll
        for (int j = 0; j < DEG1; ++j) {
            const int   dd = __shfl(dstv, j, 64);
            const float w0 = __shfl(sc0,  j, 64);
            const float w1 = __shfl(sc1,  j, 64);
            const float wgt = (lane < 32) ? w0 : w1;
            const uint2 hv = h2[(size_t)dd * 64 + lane];
            acc.x = fmaf(wgt, bf_lo(hv.x), acc.x);
            acc.y = fmaf(wgt, bf_hi(hv.x), acc.y);
            acc.z = fmaf(wgt, bf_lo(hv.y), acc.z);
            acc.w = fmaf(wgt, bf_hi(hv.y), acc.w);
        }
        // combine batches: partner lane (lane ^ 32) holds the other batch's
        // partial for the SAME dims
        float4 o;
        o.x = (acc.x + __shfl_xor(acc.x, 32, 64)) * inv;
        o.y = (acc.y + __shfl_xor(acc.y, 32, 64)) * inv;
        o.z = (acc.z + __shfl_xor(acc.z, 32, 64)) * inv;
        o.w = (acc.w + __shfl_xor(acc.w, 32, 64)) * inv;

        const int b  = lane >> 5;        // which batch's copy this lane writes
        const int dl = lane & 31;        // dim group
        *(float4*)&out[((size_t)b * N_NODES + i) * D_EMB + dl * 4] = o;
    }
}

extern "C" void kernel_launch(void* const* d_in, const int* in_sizes, int n_in,
                              void* d_out, int out_size, void* d_ws, size_t ws_size,
                              hipStream_t stream) {
    const float* X     = (const float*)d_in[0];   // (2, 10000, 128) fp32
    const float* W     = (const float*)d_in[1];   // (128, 128) fp32
    const float* Wattn = (const float*)d_in[2];   // (256, 1) fp32
    const int*   edges = (const int*)d_in[3];     // (330000, 2) int32
    float* out = (float*)d_out;                   // (2, 10000, 128) fp32

    unsigned short* wtf = (unsigned short*)d_ws;                 // 16384 bf16 = 32KB
    unsigned short* hb  = wtf + 16384;                           // (n,b) interleaved bf16
    float* s_arr = (float*)(hb + (size_t)BATCH * N_NODES * D_EMB);
    float* d_arr = s_arr + BATCH * N_NODES;

    gat_prep_kernel<<<8, 256, 0, stream>>>(W, wtf);
    gat_h_kernel<<<625, 256, 0, stream>>>(X, wtf, Wattn, hb, s_arr, d_arr);
    gat_agg_kernel<<<625, 256, 0, stream>>>((const uint2*)hb, s_arr, d_arr, edges, out);
}

// Round 5
// 91.173 us; speedup vs baseline: 1.1055x; 1.1055x over previous
//
#include <hip/hip_runtime.h>
#include <math.h>

#define N_NODES 10000
#define DEG1 33          // DEG + self-loop
#define D_EMB 128
#define F_IN 128
#define BATCH 2

typedef short s8v  __attribute__((ext_vector_type(8)));
typedef float f4v  __attribute__((ext_vector_type(4)));

// fp32 -> bf16 round-to-nearest-even (no NaN special-case; inputs are normal)
static __device__ __forceinline__ unsigned short f2bf(float f) {
    unsigned int x = __float_as_uint(f);
    unsigned int r = (x + 0x7fffu + ((x >> 16) & 1u)) >> 16;
    return (unsigned short)r;
}
static __device__ __forceinline__ float bf_lo(unsigned int u) { return __uint_as_float(u << 16); }
static __device__ __forceinline__ float bf_hi(unsigned int u) { return __uint_as_float(u & 0xffff0000u); }
static __device__ __forceinline__ float rdlane_f(float v, int l) {
    return __uint_as_float((unsigned int)__builtin_amdgcn_readlane((int)__float_as_uint(v), l));
}

// ---------------------------------------------------------------------------
// Kernel 0 (prep): pack W (128x128 fp32) into bf16 B-fragments for
// mfma_f32_16x16x32_bf16:  B[k = s*32 + (l>>4)*8 + j][n = c*16 + (l&15)]
// layout wtf[((c*4+s)*64 + l)*8 + j]  (16B/lane -> coalesced dwordx4 loads).
// ---------------------------------------------------------------------------
__global__ __launch_bounds__(256) void gat_prep_kernel(
    const float* __restrict__ W, unsigned short* __restrict__ wtf)
{
    const int c = blockIdx.x;
    const int t = threadIdx.x;
    __shared__ float xs[128 * 16];   // W[:, c*16 .. c*16+16)
    #pragma unroll
    for (int r = 0; r < 8; ++r) {
        const int k = r * 16 + (t >> 4);
        const int n = t & 15;
        xs[k * 16 + n] = W[k * 128 + c * 16 + n];
    }
    __syncthreads();
    const int s = t >> 6;    // k-step 0..3
    const int l = t & 63;    // lane
    s8v frag;
    #pragma unroll
    for (int j = 0; j < 8; ++j) {
        const int k = s * 32 + (l >> 4) * 8 + j;
        frag[j] = (short)f2bf(xs[k * 16 + (l & 15)]);
    }
    *(s8v*)&wtf[(((size_t)c * 4 + s) * 64 + l) * 8] = frag;
}

// ---------------------------------------------------------------------------
// Kernel 1 (R3 version): h = X @ W via bf16 MFMA. Wave = 16 rows x 128 cols,
// no LDS/barriers in the main loop. s = h.a_src, d = h.a_dst from fp32 accs.
// h stored bf16, batch-interleaved: hb[(n*2+b)*128 + col].
// ---------------------------------------------------------------------------
__global__ __launch_bounds__(256) void gat_h_kernel(
    const float* __restrict__ X, const unsigned short* __restrict__ wtf,
    const float* __restrict__ Wattn,
    unsigned short* __restrict__ hb, float* __restrict__ s_arr, float* __restrict__ d_arr)
{
    const int w = blockIdx.x * 4 + (threadIdx.x >> 6);   // global wave id
    if (w >= (BATCH * N_NODES) / 16) return;             // 1250 waves exactly
    const int lane = threadIdx.x & 63;
    const int quad = lane >> 4;
    const int mrow = lane & 15;
    const int row0 = w * 16;

    f4v acc[8];
    #pragma unroll
    for (int c = 0; c < 8; ++c) acc[c] = (f4v){0.f, 0.f, 0.f, 0.f};

    const float* xrow = X + (size_t)(row0 + mrow) * F_IN;
    #pragma unroll
    for (int s = 0; s < 4; ++s) {
        const int k0 = s * 32 + quad * 8;
        const float4 xa = *(const float4*)&xrow[k0];
        const float4 xbv = *(const float4*)&xrow[k0 + 4];
        s8v a;
        a[0] = (short)f2bf(xa.x);  a[1] = (short)f2bf(xa.y);
        a[2] = (short)f2bf(xa.z);  a[3] = (short)f2bf(xa.w);
        a[4] = (short)f2bf(xbv.x); a[5] = (short)f2bf(xbv.y);
        a[6] = (short)f2bf(xbv.z); a[7] = (short)f2bf(xbv.w);
        #pragma unroll
        for (int c = 0; c < 8; ++c) {
            const s8v b = *(const s8v*)&wtf[(((size_t)c * 4 + s) * 64 + lane) * 8];
            acc[c] = __builtin_amdgcn_mfma_f32_16x16x32_bf16(a, b, acc[c], 0, 0, 0);
        }
    }

    // ---- store h (bf16, interleaved (n, b)); rows never straddle the batch ----
    const int b = (row0 >= N_NODES) ? 1 : 0;
    #pragma unroll
    for (int r = 0; r < 4; ++r) {
        const int R = row0 + quad * 4 + r;
        const int n = R - b * N_NODES;
        unsigned short* dst = &hb[((size_t)n * 2 + b) * D_EMB + mrow];
        #pragma unroll
        for (int c = 0; c < 8; ++c)
            dst[c * 16] = f2bf(acc[c][r]);
    }

    // ---- s/d dots: reduce across the 16 lanes (mrow) of each quad ----
    float as[8], ad[8];
    #pragma unroll
    for (int c = 0; c < 8; ++c) {
        as[c] = Wattn[c * 16 + mrow];
        ad[c] = Wattn[D_EMB + c * 16 + mrow];
    }
    #pragma unroll
    for (int r = 0; r < 4; ++r) {
        float sv = 0.f, dv = 0.f;
        #pragma unroll
        for (int c = 0; c < 8; ++c) {
            sv = fmaf(acc[c][r], as[c], sv);
            dv = fmaf(acc[c][r], ad[c], dv);
        }
        #pragma unroll
        for (int off = 1; off < 16; off <<= 1) {
            sv += __shfl_xor(sv, off, 16);
            dv += __shfl_xor(dv, off, 16);
        }
        if (mrow == 0) {
            const int R = row0 + quad * 4 + r;
            s_arr[R] = sv;
            d_arr[R] = dv;
        }
    }
}

// ---------------------------------------------------------------------------
// Kernel 2: edge phase. ONE SINGLE-WAVE BLOCK PER NODE (10000 blocks):
// tiny VGPR footprint -> ~32 waves/CU for latency hiding on the random
// gather (hb is 5.12MB > 4MiB per-XCD L2, so many reads hit L3 ~600cyc).
// Per-edge dst/weights broadcast via readlane -> SGPR, so gathers are
// saddr-form loads with scalar-computed addresses: full 33-deep unroll of
// independent 512B loads per node. inv_denom folded into scores up front.
// ---------------------------------------------------------------------------
__global__ __launch_bounds__(64) void gat_agg_kernel(
    const uint2* __restrict__ h2, const float* __restrict__ s_arr,
    const float* __restrict__ d_arr, const int* __restrict__ edges,
    float* __restrict__ out)
{
    const int i = blockIdx.x;     // node
    const int lane = threadIdx.x; // 0..63

    int dstv = 0; float sc0 = 0.f, sc1 = 0.f;
    if (lane < DEG1) {
        dstv = edges[((size_t)i * DEG1 + lane) * 2 + 1];
        float x0 = s_arr[i] + d_arr[dstv];
        float x1 = s_arr[N_NODES + i] + d_arr[N_NODES + dstv];
        x0 = (x0 >= 0.f) ? x0 : 0.2f * x0;            // leaky_relu(0.2)
        x1 = (x1 >= 0.f) ? x1 : 0.2f * x1;
        sc0 = __expf(fminf(fmaxf(x0, -2.f), 2.f));
        sc1 = __expf(fminf(fmaxf(x1, -2.f), 2.f));
    }
    float dsum = sc0;              // denom from batch 0 only (ref semantics)
    #pragma unroll
    for (int off = 1; off < 64; off <<= 1) dsum += __shfl_xor(dsum, off, 64);
    const float inv = 1.f / dsum;
    sc0 *= inv;                    // fold inv_denom into both batches' scores
    sc1 *= inv;

    // lanes 0..31: batch-0 dims 4*lane..4*lane+3; lanes 32..63: batch-1 same dims
    float4 acc = make_float4(0.f, 0.f, 0.f, 0.f);
    #pragma unroll
    for (int j = 0; j < DEG1; ++j) {
        const int   dd = __builtin_amdgcn_readlane(dstv, j);   // SGPR
        const float w0 = rdlane_f(sc0, j);                     // SGPR
        const float w1 = rdlane_f(sc1, j);                     // SGPR
        const float wgt = (lane < 32) ? w0 : w1;
        const uint2 hv = h2[(size_t)dd * 64 + lane];           // saddr + lane*8
        acc.x = fmaf(wgt, bf_lo(hv.x), acc.x);
        acc.y = fmaf(wgt, bf_hi(hv.x), acc.y);
        acc.z = fmaf(wgt, bf_lo(hv.y), acc.z);
        acc.w = fmaf(wgt, bf_hi(hv.y), acc.w);
    }
    // combine batches: partner lane (lane ^ 32) holds the other batch's
    // partial for the SAME dims
    float4 o;
    o.x = acc.x + __shfl_xor(acc.x, 32, 64);
    o.y = acc.y + __shfl_xor(acc.y, 32, 64);
    o.z = acc.z + __shfl_xor(acc.z, 32, 64);
    o.w = acc.w + __shfl_xor(acc.w, 32, 64);

    const int b  = lane >> 5;        // which batch's copy this lane writes
    const int dl = lane & 31;        // dim group
    *(float4*)&out[((size_t)b * N_NODES + i) * D_EMB + dl * 4] = o;
}

extern "C" void kernel_launch(void* const* d_in, const int* in_sizes, int n_in,
                              void* d_out, int out_size, void* d_ws, size_t ws_size,
                              hipStream_t stream) {
    const float* X     = (const float*)d_in[0];   // (2, 10000, 128) fp32
    const float* W     = (const float*)d_in[1];   // (128, 128) fp32
    const float* Wattn = (const float*)d_in[2];   // (256, 1) fp32
    const int*   edges = (const int*)d_in[3];     // (330000, 2) int32
    float* out = (float*)d_out;                   // (2, 10000, 128) fp32

    unsigned short* wtf = (unsigned short*)d_ws;                 // 16384 bf16 = 32KB
    unsigned short* hb  = wtf + 16384;                           // (n,b) interleaved bf16
    float* s_arr = (float*)(hb + (size_t)BATCH * N_NODES * D_EMB);
    float* d_arr = s_arr + BATCH * N_NODES;

    gat_prep_kernel<<<8, 256, 0, stream>>>(W, wtf);
    gat_h_kernel<<<313, 256, 0, stream>>>(X, wtf, Wattn, hb, s_arr, d_arr);
    gat_agg_kernel<<<N_NODES, 64, 0, stream>>>((const uint2*)hb, s_arr, d_arr, edges, out);
}

// Round 7
// 90.516 us; speedup vs baseline: 1.1135x; 1.0073x over previous
//
#include <hip/hip_runtime.h>
#include <math.h>

#define N_NODES 10000
#define DEG1 33          // DEG + self-loop
#define D_EMB 128
#define F_IN 128
#define BATCH 2

typedef short s8v  __attribute__((ext_vector_type(8)));
typedef float f4v  __attribute__((ext_vector_type(4)));

// fp32 -> bf16 round-to-nearest-even (no NaN special-case; inputs are normal)
static __device__ __forceinline__ unsigned short f2bf(float f) {
    unsigned int x = __float_as_uint(f);
    unsigned int r = (x + 0x7fffu + ((x >> 16) & 1u)) >> 16;
    return (unsigned short)r;
}
static __device__ __forceinline__ float bf_lo(unsigned int u) { return __uint_as_float(u << 16); }
static __device__ __forceinline__ float bf_hi(unsigned int u) { return __uint_as_float(u & 0xffff0000u); }
static __device__ __forceinline__ float rdlane_f(float v, int l) {
    return __uint_as_float((unsigned int)__builtin_amdgcn_readlane((int)__float_as_uint(v), l));
}

// ---------------------------------------------------------------------------
// Kernel 0 (prep): pack W (128x128 fp32) into bf16 B-fragments for
// mfma_f32_16x16x32_bf16:  B[k = s*32 + (l>>4)*8 + j][n = c*16 + (l&15)]
// layout wtf[((c*4+s)*64 + l)*8 + j]  (16B/lane -> coalesced dwordx4 loads).
// ---------------------------------------------------------------------------
__global__ __launch_bounds__(256) void gat_prep_kernel(
    const float* __restrict__ W, unsigned short* __restrict__ wtf)
{
    const int c = blockIdx.x;
    const int t = threadIdx.x;
    __shared__ float xs[128 * 16];   // W[:, c*16 .. c*16+16)
    #pragma unroll
    for (int r = 0; r < 8; ++r) {
        const int k = r * 16 + (t >> 4);
        const int n = t & 15;
        xs[k * 16 + n] = W[k * 128 + c * 16 + n];
    }
    __syncthreads();
    const int s = t >> 6;    // k-step 0..3
    const int l = t & 63;    // lane
    s8v frag;
    #pragma unroll
    for (int j = 0; j < 8; ++j) {
        const int k = s * 32 + (l >> 4) * 8 + j;
        frag[j] = (short)f2bf(xs[k * 16 + (l & 15)]);
    }
    *(s8v*)&wtf[(((size_t)c * 4 + s) * 64 + l) * 8] = frag;
}

// ---------------------------------------------------------------------------
// Kernel 1 (R3/R5 version): h = X @ W via bf16 MFMA. Wave = 16 rows x 128
// cols, no LDS/barriers in the main loop. s = h.a_src, d = h.a_dst from fp32
// accumulators. h stored bf16, batch-interleaved: hb[(n*2+b)*128 + col].
// ---------------------------------------------------------------------------
__global__ __launch_bounds__(256) void gat_h_kernel(
    const float* __restrict__ X, const unsigned short* __restrict__ wtf,
    const float* __restrict__ Wattn,
    unsigned short* __restrict__ hb, float* __restrict__ s_arr, float* __restrict__ d_arr)
{
    const int w = blockIdx.x * 4 + (threadIdx.x >> 6);   // global wave id
    if (w >= (BATCH * N_NODES) / 16) return;             // 1250 waves exactly
    const int lane = threadIdx.x & 63;
    const int quad = lane >> 4;
    const int mrow = lane & 15;
    const int row0 = w * 16;

    f4v acc[8];
    #pragma unroll
    for (int c = 0; c < 8; ++c) acc[c] = (f4v){0.f, 0.f, 0.f, 0.f};

    const float* xrow = X + (size_t)(row0 + mrow) * F_IN;
    #pragma unroll
    for (int s = 0; s < 4; ++s) {
        const int k0 = s * 32 + quad * 8;
        const float4 xa = *(const float4*)&xrow[k0];
        const float4 xbv = *(const float4*)&xrow[k0 + 4];
        s8v a;
        a[0] = (short)f2bf(xa.x);  a[1] = (short)f2bf(xa.y);
        a[2] = (short)f2bf(xa.z);  a[3] = (short)f2bf(xa.w);
        a[4] = (short)f2bf(xbv.x); a[5] = (short)f2bf(xbv.y);
        a[6] = (short)f2bf(xbv.z); a[7] = (short)f2bf(xbv.w);
        #pragma unroll
        for (int c = 0; c < 8; ++c) {
            const s8v b = *(const s8v*)&wtf[(((size_t)c * 4 + s) * 64 + lane) * 8];
            acc[c] = __builtin_amdgcn_mfma_f32_16x16x32_bf16(a, b, acc[c], 0, 0, 0);
        }
    }

    // ---- store h (bf16, interleaved (n, b)); rows never straddle the batch ----
    const int b = (row0 >= N_NODES) ? 1 : 0;
    #pragma unroll
    for (int r = 0; r < 4; ++r) {
        const int R = row0 + quad * 4 + r;
        const int n = R - b * N_NODES;
        unsigned short* dst = &hb[((size_t)n * 2 + b) * D_EMB + mrow];
        #pragma unroll
        for (int c = 0; c < 8; ++c)
            dst[c * 16] = f2bf(acc[c][r]);
    }

    // ---- s/d dots: reduce across the 16 lanes (mrow) of each quad ----
    float as[8], ad[8];
    #pragma unroll
    for (int c = 0; c < 8; ++c) {
        as[c] = Wattn[c * 16 + mrow];
        ad[c] = Wattn[D_EMB + c * 16 + mrow];
    }
    #pragma unroll
    for (int r = 0; r < 4; ++r) {
        float sv = 0.f, dv = 0.f;
        #pragma unroll
        for (int c = 0; c < 8; ++c) {
            sv = fmaf(acc[c][r], as[c], sv);
            dv = fmaf(acc[c][r], ad[c], dv);
        }
        #pragma unroll
        for (int off = 1; off < 16; off <<= 1) {
            sv += __shfl_xor(sv, off, 16);
            dv += __shfl_xor(dv, off, 16);
        }
        if (mrow == 0) {
            const int R = row0 + quad * 4 + r;
            s_arr[R] = sv;
            d_arr[R] = dv;
        }
    }
}

// ---------------------------------------------------------------------------
// Kernel 2: edge phase. Wave = node, FOUR independent waves per 256-thread
// block (no barriers, no LDS): 16-workgroup/CU cap x 4 waves = full 32
// waves/CU TLP (R5's 64-thr blocks capped at 16 waves/CU). Per-edge
// dst/weights via readlane -> SGPR; gather = one saddr dwordx2 covering both
// batches' interleaved bf16 rows (512B/edge); 33-deep unrolled MLP.
// inv_denom (batch-0 denom, ref semantics) folded into scores up front;
// batches combined with one shfl_xor(32).
// ---------------------------------------------------------------------------
__global__ __launch_bounds__(256) void gat_agg_kernel(
    const uint2* __restrict__ h2, const float* __restrict__ s_arr,
    const float* __restrict__ d_arr, const int* __restrict__ edges,
    float* __restrict__ out)
{
    const int i = blockIdx.x * 4 + (threadIdx.x >> 6);   // node
    const int lane = threadIdx.x & 63;

    int dstv = 0; float sc0 = 0.f, sc1 = 0.f;
    if (lane < DEG1) {
        dstv = edges[((size_t)i * DEG1 + lane) * 2 + 1];
        float x0 = s_arr[i] + d_arr[dstv];
        float x1 = s_arr[N_NODES + i] + d_arr[N_NODES + dstv];
        x0 = (x0 >= 0.f) ? x0 : 0.2f * x0;            // leaky_relu(0.2)
        x1 = (x1 >= 0.f) ? x1 : 0.2f * x1;
        sc0 = __expf(fminf(fmaxf(x0, -2.f), 2.f));
        sc1 = __expf(fminf(fmaxf(x1, -2.f), 2.f));
    }
    float dsum = sc0;              // denom from batch 0 only (ref semantics)
    #pragma unroll
    for (int off = 1; off < 64; off <<= 1) dsum += __shfl_xor(dsum, off, 64);
    const float inv = 1.f / dsum;
    sc0 *= inv;                    // fold inv_denom into both batches' scores
    sc1 *= inv;

    // lanes 0..31: batch-0 dims 4*lane..4*lane+3; lanes 32..63: batch-1 same
    float4 acc = make_float4(0.f, 0.f, 0.f, 0.f);
    #pragma unroll
    for (int j = 0; j < DEG1; ++j) {
        const int   dd = __builtin_amdgcn_readlane(dstv, j);   // SGPR
        const float w0 = rdlane_f(sc0, j);                     // SGPR
        const float w1 = rdlane_f(sc1, j);                     // SGPR
        const float wgt = (lane < 32) ? w0 : w1;
        const uint2 hv = h2[(size_t)dd * 64 + lane];           // saddr + lane*8
        acc.x = fmaf(wgt, bf_lo(hv.x), acc.x);
        acc.y = fmaf(wgt, bf_hi(hv.x), acc.y);
        acc.z = fmaf(wgt, bf_lo(hv.y), acc.z);
        acc.w = fmaf(wgt, bf_hi(hv.y), acc.w);
    }
    // combine batches: partner lane (lane ^ 32) holds the other batch's
    // partial for the SAME dims
    float4 o;
    o.x = acc.x + __shfl_xor(acc.x, 32, 64);
    o.y = acc.y + __shfl_xor(acc.y, 32, 64);
    o.z = acc.z + __shfl_xor(acc.z, 32, 64);
    o.w = acc.w + __shfl_xor(acc.w, 32, 64);

    const int b  = lane >> 5;        // which batch's copy this lane writes
    const int dl = lane & 31;        // dim group
    *(float4*)&out[((size_t)b * N_NODES + i) * D_EMB + dl * 4] = o;
}

extern "C" void kernel_launch(void* const* d_in, const int* in_sizes, int n_in,
                              void* d_out, int out_size, void* d_ws, size_t ws_size,
                              hipStream_t stream) {
    const float* X     = (const float*)d_in[0];   // (2, 10000, 128) fp32
    const float* W     = (const float*)d_in[1];   // (128, 128) fp32
    const float* Wattn = (const float*)d_in[2];   // (256, 1) fp32
    const int*   edges = (const int*)d_in[3];     // (330000, 2) int32
    float* out = (float*)d_out;                   // (2, 10000, 128) fp32

    unsigned short* wtf = (unsigned short*)d_ws;                 // 16384 bf16 = 32KB
    unsigned short* hb  = wtf + 16384;                           // (n,b) interleaved bf16
    float* s_arr = (float*)(hb + (size_t)BATCH * N_NODES * D_EMB);
    float* d_arr = s_arr + BATCH * N_NODES;

    gat_prep_kernel<<<8, 256, 0, stream>>>(W, wtf);
    gat_h_kernel<<<313, 256, 0, stream>>>(X, wtf, Wattn, hb, s_arr, d_arr);
    gat_agg_kernel<<<N_NODES / 4, 256, 0, stream>>>((const uint2*)hb, s_arr, d_arr, edges, out);
}